// Round 1
// baseline (249.556 us; speedup 1.0000x reference)
//
#include <hip/hip_runtime.h>
#include <hip/hip_fp16.h>

typedef _Float16 f16x8 __attribute__((ext_vector_type(8)));
typedef _Float16 f16x4 __attribute__((ext_vector_type(4)));
typedef float f32x4 __attribute__((ext_vector_type(4)));

// ---------------------------------------------------------------------------
// Fused: scores = (MK^T @ Q) / (norm[d]+1e-6);  O = MV @ scores.
// One block per (b,h): 256 threads = 4 waves, mfma_f32_16x16x32_f16.
// LDS tiles stored K-contiguous (transposed where needed), rows padded to 72
// halfwords (144 B) so 16-lane b128 reads are <=2-way bank aliased (free).
// ---------------------------------------------------------------------------
__global__ __launch_bounds__(256) void fused_attn(
    const float* __restrict__ q, const float* __restrict__ mk,
    const float* __restrict__ mnorm, const float* __restrict__ mv,
    float* __restrict__ out_mo, float* __restrict__ out_sc)
{
    __shared__ _Float16 qT [64][72];   // qT[d][n]  = q[n][d]
    __shared__ _Float16 mkT[64][72];   // mkT[m][n] = mk[n][m]
    __shared__ _Float16 mvs[64][72];   // mvs[n][m] = mv[n][m]
    __shared__ _Float16 sT [64][72];   // sT[d][m]  = scores[m][d] (divided)

    const int t  = threadIdx.x;
    const int bh = blockIdx.x;
    const int h  = bh & 63;
    const float* qb  = q  + (size_t)bh * 4096;
    const float* mkb = mk + h * 4096;
    const float* mvb = mv + h * 4096;

    const int r0 = t >> 4;            // 0..15
    const int c0 = (t & 15) << 2;     // 0,4,..,60
#pragma unroll
    for (int qq = 0; qq < 4; ++qq) {
        const int row = r0 + 16 * qq;
        float4 qv = *(const float4*)(qb  + row * 64 + c0);
        float4 kv = *(const float4*)(mkb + row * 64 + c0);
        float4 vv = *(const float4*)(mvb + row * 64 + c0);
        qT[c0 + 0][row] = (_Float16)qv.x;
        qT[c0 + 1][row] = (_Float16)qv.y;
        qT[c0 + 2][row] = (_Float16)qv.z;
        qT[c0 + 3][row] = (_Float16)qv.w;
        mkT[c0 + 0][row] = (_Float16)kv.x;
        mkT[c0 + 1][row] = (_Float16)kv.y;
        mkT[c0 + 2][row] = (_Float16)kv.z;
        mkT[c0 + 3][row] = (_Float16)kv.w;
        f16x4 pv;
        pv[0] = (_Float16)vv.x; pv[1] = (_Float16)vv.y;
        pv[2] = (_Float16)vv.z; pv[3] = (_Float16)vv.w;
        *(f16x4*)&mvs[row][c0] = pv;
    }
    __syncthreads();

    const int w  = t >> 6;   // wave id: output row-stripe [16w,16w+16)
    const int l  = t & 63;
    const int lr = l & 15;   // A row sel / B-D col sel
    const int lk = l >> 4;   // k-group
    const size_t gbase = (size_t)bh * 4096;

    // S[m,d] = sum_n mkT[m][n] * qT[d][n]
    f32x4 acc[4] = {};
#pragma unroll
    for (int kn = 0; kn < 2; ++kn) {
        f16x8 a = *(const f16x8*)&mkT[16 * w + lr][kn * 32 + lk * 8];
#pragma unroll
        for (int di = 0; di < 4; ++di) {
            f16x8 b = *(const f16x8*)&qT[16 * di + lr][kn * 32 + lk * 8];
            acc[di] = __builtin_amdgcn_mfma_f32_16x16x32_f16(a, b, acc[di], 0, 0, 0);
        }
    }

    const int m0 = 16 * w + 4 * lk;   // D rows: m0..m0+3
#pragma unroll
    for (int di = 0; di < 4; ++di) {
        const int d = 16 * di + lr;
        const float scale = 1.0f / (mnorm[d] + 1e-6f);
        f16x4 pk;
#pragma unroll
        for (int r = 0; r < 4; ++r) {
            float sv = acc[di][r] * scale;
            out_sc[gbase + (size_t)(m0 + r) * 64 + d] = sv;
            pk[r] = (_Float16)sv;
        }
        *(f16x4*)&sT[d][m0] = pk;
    }
    __syncthreads();

    // O[n,d] = sum_m mvs[n][m] * sT[d][m]
    f32x4 acc2[4] = {};
#pragma unroll
    for (int kn = 0; kn < 2; ++kn) {
        f16x8 a = *(const f16x8*)&mvs[16 * w + lr][kn * 32 + lk * 8];
#pragma unroll
        for (int di = 0; di < 4; ++di) {
            f16x8 b = *(const f16x8*)&sT[16 * di + lr][kn * 32 + lk * 8];
            acc2[di] = __builtin_amdgcn_mfma_f32_16x16x32_f16(a, b, acc2[di], 0, 0, 0);
        }
    }
#pragma unroll
    for (int di = 0; di < 4; ++di) {
        const int d = 16 * di + lr;
#pragma unroll
        for (int r = 0; r < 4; ++r)
            out_mo[gbase + (size_t)(m0 + r) * 64 + d] = acc2[di][r];
    }
}

// ---------------------------------------------------------------------------
// Stage 1 reduction over the 8192 (b,h) tiles:
//   skp/svp: elementwise partial sums of key/value 64x64 tiles
//   pbp[m]:  partial of sum_{tiles} sum_d (sum_n key[n,d]) * value[m,d]
// Deterministic (fixed-order, no atomics).
// ---------------------------------------------------------------------------
__global__ __launch_bounds__(256) void reduce1(
    const float* __restrict__ key, const float* __restrict__ val,
    float* __restrict__ skp, float* __restrict__ svp, float* __restrict__ pbp,
    const int nb)
{
    __shared__ float ktile[64][68];
    __shared__ float red[256];
    __shared__ float ks_s[64];
    const int t   = threadIdx.x;
    const int blk = blockIdx.x;
    const int r0  = t >> 4;
    const int c0  = (t & 15) << 2;
    float4 ska[4] = {};
    float4 sva[4] = {};
    float  pba[4] = {0.f, 0.f, 0.f, 0.f};

    for (int i = blk; i < 8192; i += nb) {
        const float* kb = key + (size_t)i * 4096;
        const float* vb = val + (size_t)i * 4096;
        float4 vv[4];
#pragma unroll
        for (int qq = 0; qq < 4; ++qq) {
            const int row = r0 + 16 * qq;
            float4 kv = *(const float4*)(kb + row * 64 + c0);
            vv[qq]    = *(const float4*)(vb + row * 64 + c0);
            ska[qq].x += kv.x; ska[qq].y += kv.y; ska[qq].z += kv.z; ska[qq].w += kv.w;
            sva[qq].x += vv[qq].x; sva[qq].y += vv[qq].y; sva[qq].z += vv[qq].z; sva[qq].w += vv[qq].w;
            *(float4*)&ktile[row][c0] = kv;
        }
        __syncthreads();
        // column sums of key tile: ks[d] = sum_n key[n][d]
        const int d  = t & 63;
        const int rr = (t >> 6) * 16;
        float p = 0.f;
#pragma unroll
        for (int r = 0; r < 16; ++r) p += ktile[rr + r][d];
        red[t] = p;
        __syncthreads();
        if (t < 64) ks_s[t] = red[t] + red[t + 64] + red[t + 128] + red[t + 192];
        __syncthreads();
        // binding partial: rows m = r0 + 16*qq, 16 consecutive lanes share m
#pragma unroll
        for (int qq = 0; qq < 4; ++qq) {
            float pq = vv[qq].x * ks_s[c0]     + vv[qq].y * ks_s[c0 + 1]
                     + vv[qq].z * ks_s[c0 + 2] + vv[qq].w * ks_s[c0 + 3];
            pq += __shfl_xor(pq, 1);
            pq += __shfl_xor(pq, 2);
            pq += __shfl_xor(pq, 4);
            pq += __shfl_xor(pq, 8);
            pba[qq] += pq;
        }
        // next-iter ktile writes are ordered behind this iter's reads by the
        // barrier chain above (reads of red/ktile complete before their barrier)
    }
    const size_t pb4 = (size_t)blk * 4096;
#pragma unroll
    for (int qq = 0; qq < 4; ++qq) {
        *(float4*)(skp + pb4 + 4 * t + 1024 * qq) = ska[qq];
        *(float4*)(svp + pb4 + 4 * t + 1024 * qq) = sva[qq];
    }
    if ((t & 15) == 0) {
#pragma unroll
        for (int qq = 0; qq < 4; ++qq)
            pbp[blk * 64 + r0 + 16 * qq] = pba[qq];
    }
}

// Stage 2: reduce nb partials -> totals (8256 elements)
__global__ __launch_bounds__(256) void reduce2(
    const float* __restrict__ skp, const float* __restrict__ svp,
    const float* __restrict__ pbp,
    float* __restrict__ sk_tot, float* __restrict__ sv_tot,
    float* __restrict__ pb_tot, const int nb)
{
    const int e = blockIdx.x * 256 + threadIdx.x;
    if (e < 4096) {
        float s = 0.f;
        for (int n = 0; n < nb; ++n) s += skp[(size_t)n * 4096 + e];
        sk_tot[e] = s;
    } else if (e < 8192) {
        const int e2 = e - 4096;
        float s = 0.f;
        for (int n = 0; n < nb; ++n) s += svp[(size_t)n * 4096 + e2];
        sv_tot[e2] = s;
    } else if (e < 8256) {
        const int e2 = e - 8192;
        float s = 0.f;
        for (int n = 0; n < nb; ++n) s += pbp[n * 64 + e2];
        pb_tot[e2] = s;
    }
}

// Stage 3: norms, conditional compression factor, final small outputs
__global__ __launch_bounds__(256) void finalize(
    const float* __restrict__ sk_tot, const float* __restrict__ sv_tot,
    const float* __restrict__ pb_tot, const float* __restrict__ mnorm,
    const float* __restrict__ crate,
    float* __restrict__ out_nmk, float* __restrict__ out_nmn)
{
    __shared__ float fac_s[64];
    __shared__ float nmn_s[64];
    const int t = threadIdx.x;
    if (t < 64) {
        float ss = 0.f;
        for (int d = 0; d < 64; ++d) {
            float m = sk_tot[t * 64 + d] * (1.0f / 8192.0f);
            ss += m * m;
        }
        nmn_s[t] = mnorm[t] + sqrtf(ss);
        float v = nmn_s[t];
        for (int off = 32; off; off >>= 1) v += __shfl_xor(v, off);
        const float mean = v * (1.0f / 64.0f);
        const float f = (mean > 0.9f) ? crate[t] : 1.0f;
        fac_s[t] = f;
        out_nmn[t] = nmn_s[t] * f;
    }
    __syncthreads();
    for (int e = t; e < 4096; e += 256) {
        const int j = e >> 6;
        const float mb = pb_tot[j] * (1.0f / 524288.0f);   // mean binding
        const float mv = sv_tot[e] * (1.0f / 8192.0f);     // mean value
        out_nmk[e] = mb * mv * fac_s[j];
    }
}

extern "C" void kernel_launch(void* const* d_in, const int* in_sizes, int n_in,
                              void* d_out, int out_size, void* d_ws, size_t ws_size,
                              hipStream_t stream) {
    const float* q  = (const float*)d_in[0];
    const float* k  = (const float*)d_in[1];
    const float* v  = (const float*)d_in[2];
    const float* mk = (const float*)d_in[3];
    const float* mn = (const float*)d_in[4];
    const float* mv = (const float*)d_in[5];
    const float* cr = (const float*)d_in[6];

    float* out     = (float*)d_out;
    float* out_mo  = out;                    // [128,64,64,64]
    float* out_sc  = out + 33554432;         // [128,64,64,64]
    float* out_nmk = out + 67108864;         // [64,64]
    float* out_nmn = out + 67112960;         // [64]

    float* ws      = (float*)d_ws;
    float* sk_tot  = ws;
    float* sv_tot  = ws + 4096;
    float* pb_tot  = ws + 8192;
    float* part    = ws + 8256;
    const size_t avail = (ws_size / 4 > 8256) ? (ws_size / 4 - 8256) : 0;
    int nb = (int)(avail / 8256);
    if (nb > 256) nb = 256;
    if (nb < 1)   nb = 1;
    float* skp = part;
    float* svp = part + (size_t)nb * 4096;
    float* pbp = svp  + (size_t)nb * 4096;

    hipLaunchKernelGGL(fused_attn, dim3(8192), dim3(256), 0, stream,
                       q, mk, mn, mv, out_mo, out_sc);
    hipLaunchKernelGGL(reduce1, dim3(nb), dim3(256), 0, stream,
                       k, v, skp, svp, pbp, nb);
    hipLaunchKernelGGL(reduce2, dim3(33), dim3(256), 0, stream,
                       skp, svp, pbp, sk_tot, sv_tot, pb_tot, nb);
    hipLaunchKernelGGL(finalize, dim3(1), dim3(256), 0, stream,
                       sk_tot, sv_tot, pb_tot, mn, cr, out_nmk, out_nmn);
}

// Round 2
// 186.841 us; speedup vs baseline: 1.3357x; 1.3357x over previous
//
#include <hip/hip_runtime.h>
#include <hip/hip_fp16.h>

typedef _Float16 f16x8 __attribute__((ext_vector_type(8)));
typedef _Float16 f16x4 __attribute__((ext_vector_type(4)));
typedef float f32x4 __attribute__((ext_vector_type(4)));

__device__ __forceinline__ f32x4 ntld(const float* p) {
    return __builtin_nontemporal_load((const f32x4*)p);
}
__device__ __forceinline__ f32x4 ld4(const float* p) {
    return *(const f32x4*)p;
}
__device__ __forceinline__ void ntst(float* p, float v) {
    __builtin_nontemporal_store(v, p);
}

// ---------------------------------------------------------------------------
// Mega kernel. Blocks [0, nbR): reduction path over key/value tiles.
// Blocks [nbR, nbR+8192): fused attention path, h-major so that concurrently
// resident blocks share the same head's mk/mv (keeps them L2-hot while q/out
// stream with non-temporal hints).
// ---------------------------------------------------------------------------
__global__ __launch_bounds__(256) void mega(
    const float* __restrict__ q,   const float* __restrict__ key,
    const float* __restrict__ val, const float* __restrict__ mk,
    const float* __restrict__ mnorm, const float* __restrict__ mv,
    float* __restrict__ out_mo, float* __restrict__ out_sc,
    float* __restrict__ skp, float* __restrict__ svp, float* __restrict__ pbp,
    const int nbR)
{
    __shared__ union SM {
        struct { _Float16 qT[64][72]; _Float16 mkT[64][72]; } f;   // sT aliases qT
        struct { float ktile[64][68]; float red[256]; float ks[64]; } r;
    } sm;

    const int t   = threadIdx.x;
    const int bid = blockIdx.x;
    const int r0  = t >> 4;            // 0..15
    const int c0  = (t & 15) << 2;     // 0,4,..,60

    if (bid < nbR) {
        // ================= reduction path =================
        f32x4 ska[4] = {}; f32x4 sva[4] = {};
        float pba[4] = {0.f, 0.f, 0.f, 0.f};
        f32x4 ka[4], va[4];
        int i = bid;
#pragma unroll
        for (int qq = 0; qq < 4; ++qq) {
            const int row = r0 + 16 * qq;
            ka[qq] = ntld(key + (size_t)i * 4096 + row * 64 + c0);
            va[qq] = ntld(val + (size_t)i * 4096 + row * 64 + c0);
        }
        while (true) {
            const int inx = i + nbR;
            const bool more = (inx < 8192);
            f32x4 kn4[4], vn4[4];
            if (more) {
#pragma unroll
                for (int qq = 0; qq < 4; ++qq) {
                    const int row = r0 + 16 * qq;
                    kn4[qq] = ntld(key + (size_t)inx * 4096 + row * 64 + c0);
                    vn4[qq] = ntld(val + (size_t)inx * 4096 + row * 64 + c0);
                }
            }
#pragma unroll
            for (int qq = 0; qq < 4; ++qq) {
                const int row = r0 + 16 * qq;
                ska[qq] += ka[qq];
                sva[qq] += va[qq];
                *(f32x4*)&sm.r.ktile[row][c0] = ka[qq];
            }
            __syncthreads();
            {   // column sums ks[d] = sum_n ktile[n][d]
                const int d  = t & 63;
                const int rr = (t >> 6) * 16;
                float p = 0.f;
#pragma unroll
                for (int r = 0; r < 16; ++r) p += sm.r.ktile[rr + r][d];
                sm.r.red[t] = p;
            }
            __syncthreads();
            if (t < 64)
                sm.r.ks[t] = sm.r.red[t] + sm.r.red[t + 64] + sm.r.red[t + 128] + sm.r.red[t + 192];
            __syncthreads();
#pragma unroll
            for (int qq = 0; qq < 4; ++qq) {
                float pq = va[qq][0] * sm.r.ks[c0]     + va[qq][1] * sm.r.ks[c0 + 1]
                         + va[qq][2] * sm.r.ks[c0 + 2] + va[qq][3] * sm.r.ks[c0 + 3];
                pq += __shfl_xor(pq, 1);
                pq += __shfl_xor(pq, 2);
                pq += __shfl_xor(pq, 4);
                pq += __shfl_xor(pq, 8);
                pba[qq] += pq;
            }
            if (!more) break;
#pragma unroll
            for (int qq = 0; qq < 4; ++qq) { ka[qq] = kn4[qq]; va[qq] = vn4[qq]; }
            i = inx;
        }
        const size_t pb4 = (size_t)bid * 4096;
#pragma unroll
        for (int qq = 0; qq < 4; ++qq) {
            *(f32x4*)(skp + pb4 + 4 * t + 1024 * qq) = ska[qq];
            *(f32x4*)(svp + pb4 + 4 * t + 1024 * qq) = sva[qq];
        }
        if ((t & 15) == 0) {
#pragma unroll
            for (int qq = 0; qq < 4; ++qq)
                pbp[bid * 64 + r0 + 16 * qq] = pba[qq];
        }
        return;
    }

    // ================= fused attention path =================
    const int fid = bid - nbR;
    const int h   = fid >> 7;          // h-major: neighbors share head
    const int b   = fid & 127;
    const int bh  = b * 64 + h;
    const float* qb  = q  + (size_t)bh * 4096;
    const float* mkb = mk + h * 4096;
    const float* mvb = mv + h * 4096;

    const int w  = t >> 6;   // wave id
    const int l  = t & 63;
    const int lr = l & 15;
    const int lk = l >> 4;
    const size_t gbase = (size_t)bh * 4096;

    // prefetch mv A-fragments (rows n = 16w+lr, cols lk*8 + {0..7} + kn*32), L2-hot
    f32x4 mva[4];
    {
        const float* rowp = mvb + (16 * w + lr) * 64 + lk * 8;
        mva[0] = ld4(rowp);      mva[1] = ld4(rowp + 4);
        mva[2] = ld4(rowp + 32); mva[3] = ld4(rowp + 36);
    }

    // stage q (nt, streaming) and mk (cached) transposed into LDS
#pragma unroll
    for (int qq = 0; qq < 4; ++qq) {
        const int row = r0 + 16 * qq;
        f32x4 qv = ntld(qb + row * 64 + c0);
        f32x4 kv = ld4(mkb + row * 64 + c0);
#pragma unroll
        for (int j = 0; j < 4; ++j) {
            sm.f.qT [c0 + j][row] = (_Float16)qv[j];
            sm.f.mkT[c0 + j][row] = (_Float16)kv[j];
        }
    }
    __syncthreads();

    // S[m,d] = sum_n mkT[m][n] * qT[d][n]
    f32x4 acc[4] = {};
#pragma unroll
    for (int kn = 0; kn < 2; ++kn) {
        f16x8 a = *(const f16x8*)&sm.f.mkT[16 * w + lr][kn * 32 + lk * 8];
#pragma unroll
        for (int di = 0; di < 4; ++di) {
            f16x8 bfr = *(const f16x8*)&sm.f.qT[16 * di + lr][kn * 32 + lk * 8];
            acc[di] = __builtin_amdgcn_mfma_f32_16x16x32_f16(a, bfr, acc[di], 0, 0, 0);
        }
    }
    __syncthreads();   // all phase-1 LDS reads done; qT region may be reused as sT

    _Float16* sT = &sm.f.qT[0][0];     // sT[d][m] at sT[d*72+m]
    const int m0 = 16 * w + 4 * lk;
#pragma unroll
    for (int di = 0; di < 4; ++di) {
        const int d = 16 * di + lr;
        const float scale = 1.0f / (mnorm[d] + 1e-6f);
        f16x4 pk;
#pragma unroll
        for (int r = 0; r < 4; ++r) {
            float sv = acc[di][r] * scale;
            ntst(out_sc + gbase + (size_t)(m0 + r) * 64 + d, sv);
            pk[r] = (_Float16)sv;
        }
        *(f16x4*)(sT + d * 72 + m0) = pk;
    }
    __syncthreads();

    // O[n,d] = sum_m mv[n][m] * sT[d][m]   (A from registers)
    f16x8 a2[2];
#pragma unroll
    for (int kn = 0; kn < 2; ++kn) {
        f16x8 vv;
#pragma unroll
        for (int j = 0; j < 4; ++j) {
            vv[j]     = (_Float16)mva[2 * kn][j];
            vv[j + 4] = (_Float16)mva[2 * kn + 1][j];
        }
        a2[kn] = vv;
    }
    f32x4 acc2[4] = {};
#pragma unroll
    for (int kn = 0; kn < 2; ++kn) {
#pragma unroll
        for (int di = 0; di < 4; ++di) {
            f16x8 bfr = *(const f16x8*)(sT + (16 * di + lr) * 72 + kn * 32 + lk * 8);
            acc2[di] = __builtin_amdgcn_mfma_f32_16x16x32_f16(a2[kn], bfr, acc2[di], 0, 0, 0);
        }
    }
#pragma unroll
    for (int di = 0; di < 4; ++di) {
        const int d = 16 * di + lr;
#pragma unroll
        for (int r = 0; r < 4; ++r)
            ntst(out_mo + gbase + (size_t)(m0 + r) * 64 + d, acc2[di][r]);
    }
}

// Stage 2: 264 blocks = 33 element-strips x 8 n-chunks -> p2[8][8256]
__global__ __launch_bounds__(256) void reduce2(
    const float* __restrict__ skp, const float* __restrict__ svp,
    const float* __restrict__ pbp, float* __restrict__ p2,
    const int nbR, const int clen)
{
    const int bi = blockIdx.x;
    const int c  = bi / 33;
    const int e  = (bi % 33) * 256 + threadIdx.x;
    if (e >= 8256) return;
    const int n0 = c * clen;
    int n1 = n0 + clen; if (n1 > nbR) n1 = nbR;
    float s = 0.f;
    if (e < 4096) {
        for (int n = n0; n < n1; ++n) s += skp[(size_t)n * 4096 + e];
    } else if (e < 8192) {
        const int e2 = e - 4096;
        for (int n = n0; n < n1; ++n) s += svp[(size_t)n * 4096 + e2];
    } else {
        const int e2 = e - 8192;
        for (int n = n0; n < n1; ++n) s += pbp[n * 64 + e2];
    }
    p2[c * 8256 + e] = s;
}

// Stage 3: sum the 8 chunks -> tot[8256] = {sk_tot[4096], sv_tot[4096], pb_tot[64]}
__global__ __launch_bounds__(256) void reduce3(
    const float* __restrict__ p2, float* __restrict__ tot)
{
    const int e = blockIdx.x * 256 + threadIdx.x;
    if (e >= 8256) return;
    float s = 0.f;
#pragma unroll
    for (int c = 0; c < 8; ++c) s += p2[c * 8256 + e];
    tot[e] = s;
}

// Stage 4: norms, conditional compression factor, final small outputs
__global__ __launch_bounds__(256) void finalize(
    const float* __restrict__ tot, const float* __restrict__ mnorm,
    const float* __restrict__ crate,
    float* __restrict__ out_nmk, float* __restrict__ out_nmn)
{
    __shared__ float fac_s[64];
    const float* sk_tot = tot;
    const float* sv_tot = tot + 4096;
    const float* pb_tot = tot + 8192;
    const int t = threadIdx.x;
    if (t < 64) {
        float ss = 0.f;
        for (int d = 0; d < 64; ++d) {
            float m = sk_tot[t * 64 + d] * (1.0f / 8192.0f);
            ss += m * m;
        }
        const float nmn = mnorm[t] + sqrtf(ss);
        float v = nmn;
        for (int off = 32; off; off >>= 1) v += __shfl_xor(v, off);
        const float mean = v * (1.0f / 64.0f);
        const float f = (mean > 0.9f) ? crate[t] : 1.0f;
        fac_s[t] = f;
        out_nmn[t] = nmn * f;
    }
    __syncthreads();
    for (int e = t; e < 4096; e += 256) {
        const int j = e >> 6;
        const float mb = pb_tot[j] * (1.0f / 524288.0f);   // mean binding
        const float mv = sv_tot[e] * (1.0f / 8192.0f);     // mean value
        out_nmk[e] = mb * mv * fac_s[j];
    }
}

extern "C" void kernel_launch(void* const* d_in, const int* in_sizes, int n_in,
                              void* d_out, int out_size, void* d_ws, size_t ws_size,
                              hipStream_t stream) {
    const float* q  = (const float*)d_in[0];
    const float* k  = (const float*)d_in[1];
    const float* v  = (const float*)d_in[2];
    const float* mk = (const float*)d_in[3];
    const float* mn = (const float*)d_in[4];
    const float* mv = (const float*)d_in[5];
    const float* cr = (const float*)d_in[6];

    float* out     = (float*)d_out;
    float* out_mo  = out;                    // [128,64,64,64]
    float* out_sc  = out + 33554432;         // [128,64,64,64]
    float* out_nmk = out + 67108864;         // [64,64]
    float* out_nmn = out + 67112960;         // [64]

    float* ws   = (float*)d_ws;
    float* tot  = ws;                        // 8256
    float* p2   = ws + 8256;                 // 8*8256 = 66048
    float* part = ws + 74304;
    const size_t wsf = ws_size / 4;
    const size_t avail = (wsf > 74304) ? (wsf - 74304) : 0;
    int nb = (int)(avail / 8256);
    if (nb > 1024) nb = 1024;
    if (nb < 1)    nb = 1;
    float* skp = part;
    float* svp = part + (size_t)nb * 4096;
    float* pbp = svp  + (size_t)nb * 4096;
    const int clen = (nb + 7) / 8;

    hipLaunchKernelGGL(mega, dim3(nb + 8192), dim3(256), 0, stream,
                       q, k, v, mk, mn, mv, out_mo, out_sc, skp, svp, pbp, nb);
    hipLaunchKernelGGL(reduce2, dim3(264), dim3(256), 0, stream,
                       skp, svp, pbp, p2, nb, clen);
    hipLaunchKernelGGL(reduce3, dim3(33), dim3(256), 0, stream,
                       p2, tot);
    hipLaunchKernelGGL(finalize, dim3(1), dim3(256), 0, stream,
                       tot, mn, cr, out_nmk, out_nmn);
}